// Round 1
// baseline (517.943 us; speedup 1.0000x reference)
//
#include <hip/hip_runtime.h>

#define DIM 64

// h = x @ W   (x: [N,64], W: [64,64])
__global__ void gcn_matmul(const float* __restrict__ x, const float* __restrict__ W,
                           float* __restrict__ h, int N) {
    __shared__ float Wl[DIM][DIM];
    __shared__ float xs[4][DIM];
    int tid = threadIdx.x;
    for (int i = tid; i < DIM * DIM; i += 256) Wl[i / DIM][i % DIM] = W[i];
    int node0 = blockIdx.x * 4;
    int gidx = node0 * DIM + tid;
    xs[tid / DIM][tid % DIM] = (gidx < N * DIM) ? x[gidx] : 0.f;
    __syncthreads();
    int nl = tid / DIM, d = tid % DIM;
    int node = node0 + nl;
    if (node < N) {
        float acc = 0.f;
#pragma unroll
        for (int k = 0; k < DIM; ++k) acc += xs[nl][k] * Wl[k][d];
        h[node * DIM + d] = acc;
    }
}

__global__ void deg_init(float* __restrict__ deg, int N) {
    int i = blockIdx.x * 256 + threadIdx.x;
    if (i < N) deg[i] = 1.0f;  // self loop
}

__global__ void deg_acc(const int* __restrict__ ei, float* __restrict__ deg, int E) {
    int e = blockIdx.x * 256 + threadIdx.x;
    if (e < E) atomicAdd(&deg[ei[E + e]], 1.0f);  // dst row
}

// dinv = rsqrt(deg); agg(=d_out) initialized with self-loop contribution h * dinv^2
__global__ void agg_init(const float* __restrict__ h, const float* __restrict__ deg,
                         float* __restrict__ dinv, float* __restrict__ agg, int N) {
    int idx = blockIdx.x * 256 + threadIdx.x;
    if (idx < N * DIM) {
        int n = idx >> 6, d = idx & 63;
        float di = rsqrtf(deg[n]);
        if (d == 0) dinv[n] = di;
        agg[idx] = h[idx] * (di * di);
    }
}

// per (edge, dim): agg[dst][d] += h[src][d] * dinv[src]*dinv[dst]
__global__ void edge_scatter(const int* __restrict__ ei, const float* __restrict__ h,
                             const float* __restrict__ dinv, float* __restrict__ agg, int E) {
    int idx = blockIdx.x * 256 + threadIdx.x;
    int e = idx >> 6, d = idx & 63;
    if (e < E) {
        int s = ei[e];
        int t = ei[E + e];
        float norm = dinv[s] * dinv[t];
        atomicAdd(&agg[t * DIM + d], h[s * DIM + d] * norm);
    }
}

// out = x + relu(agg + b), in place on d_out
__global__ void epilogue(const float* __restrict__ x, const float* __restrict__ b,
                         float* __restrict__ out, int N) {
    int idx = blockIdx.x * 256 + threadIdx.x;
    if (idx < N * DIM) {
        float v = out[idx] + b[idx & 63];
        out[idx] = x[idx] + fmaxf(v, 0.f);
    }
}

extern "C" void kernel_launch(void* const* d_in, const int* in_sizes, int n_in,
                              void* d_out, int out_size, void* d_ws, size_t ws_size,
                              hipStream_t stream) {
    const float* x = (const float*)d_in[0];
    const int* ei  = (const int*)d_in[1];
    const float* W = (const float*)d_in[2];
    const float* b = (const float*)d_in[3];
    float* out = (float*)d_out;

    int N = in_sizes[0] / DIM;
    int E = in_sizes[1] / 2;

    char* ws = (char*)d_ws;
    float* h    = (float*)ws;                               // N*64 floats
    float* deg  = (float*)(ws + (size_t)N * DIM * sizeof(float));
    float* dinv = deg + N;

    gcn_matmul<<<(N + 3) / 4, 256, 0, stream>>>(x, W, h, N);
    deg_init<<<(N + 255) / 256, 256, 0, stream>>>(deg, N);
    deg_acc<<<(E + 255) / 256, 256, 0, stream>>>(ei, deg, E);
    agg_init<<<(N * DIM + 255) / 256, 256, 0, stream>>>(h, deg, dinv, out, N);

    long sthreads = (long)E * DIM;
    edge_scatter<<<(int)((sthreads + 255) / 256), 256, 0, stream>>>(ei, h, dinv, out, E);

    epilogue<<<(N * DIM + 255) / 256, 256, 0, stream>>>(x, b, out, N);
}

// Round 2
// 365.115 us; speedup vs baseline: 1.4186x; 1.4186x over previous
//
#include <hip/hip_runtime.h>

#define DIM 64

// h = x @ W   (x: [N,64], W: [64,64])
__global__ void gcn_matmul(const float* __restrict__ x, const float* __restrict__ W,
                           float* __restrict__ h, int N) {
    __shared__ float Wl[DIM][DIM];
    __shared__ float xs[4][DIM];
    int tid = threadIdx.x;
    for (int i = tid; i < DIM * DIM; i += 256) Wl[i / DIM][i % DIM] = W[i];
    int node0 = blockIdx.x * 4;
    int gidx = node0 * DIM + tid;
    xs[tid / DIM][tid % DIM] = (gidx < N * DIM) ? x[gidx] : 0.f;
    __syncthreads();
    int nl = tid / DIM, d = tid % DIM;
    int node = node0 + nl;
    if (node < N) {
        float acc = 0.f;
#pragma unroll
        for (int k = 0; k < DIM; ++k) acc += xs[nl][k] * Wl[k][d];
        h[node * DIM + d] = acc;
    }
}

__global__ void zero_i32(int* __restrict__ p, int n) {
    int i = blockIdx.x * 256 + threadIdx.x;
    if (i < n) p[i] = 0;
}

// cnt[dst]++ per edge (int atomics)
__global__ void count_dst(const int* __restrict__ ei, int* __restrict__ cnt, int E) {
    int e = blockIdx.x * 256 + threadIdx.x;
    if (e < E) atomicAdd(&cnt[ei[E + e]], 1);
}

// dinv[n] = rsqrt(deg_with_selfloop)
__global__ void calc_dinv(const int* __restrict__ cnt, float* __restrict__ dinv, int N) {
    int i = blockIdx.x * 256 + threadIdx.x;
    if (i < N) dinv[i] = rsqrtf((float)cnt[i] + 1.0f);
}

// exclusive scan, step 1: per-block (256 elems) Hillis-Steele
__global__ void scan_block(const int* __restrict__ cnt, int* __restrict__ off,
                           int* __restrict__ bsum, int N) {
    __shared__ int sh[256];
    int tid = threadIdx.x;
    int i = blockIdx.x * 256 + tid;
    int v = (i < N) ? cnt[i] : 0;
    sh[tid] = v;
    __syncthreads();
    for (int d = 1; d < 256; d <<= 1) {
        int t = (tid >= d) ? sh[tid - d] : 0;
        __syncthreads();
        sh[tid] += t;
        __syncthreads();
    }
    if (i < N) off[i] = sh[tid] - v;
    if (tid == 255) bsum[blockIdx.x] = sh[255];
}

// step 2: single-block exclusive scan of block sums (nb <= 512)
__global__ void scan_bsums(int* __restrict__ bsum, int nb) {
    __shared__ int sh[512];
    int tid = threadIdx.x;
    int v = (tid < nb) ? bsum[tid] : 0;
    sh[tid] = v;
    __syncthreads();
    for (int d = 1; d < 512; d <<= 1) {
        int t = (tid >= d) ? sh[tid - d] : 0;
        __syncthreads();
        sh[tid] += t;
        __syncthreads();
    }
    if (tid < nb) bsum[tid] = sh[tid] - v;
}

// step 3: add block offsets; also materialize cursor copy for fill pass
__global__ void scan_add(int* __restrict__ off, int* __restrict__ cursor,
                         const int* __restrict__ bsum, int N) {
    int i = blockIdx.x * 256 + threadIdx.x;
    if (i < N) {
        int o = off[i] + bsum[blockIdx.x];
        off[i] = o;
        cursor[i] = o;
    }
}

// adj[pos] = src, grouped by dst
__global__ void fill_adj(const int* __restrict__ ei, int* __restrict__ cursor,
                         int* __restrict__ adj, int E) {
    int e = blockIdx.x * 256 + threadIdx.x;
    if (e < E) {
        int s = ei[e];
        int t = ei[E + e];
        int p = atomicAdd(&cursor[t], 1);
        adj[p] = s;
    }
}

// one wave per node: acc = h[n]*dinv[n] + sum_s h[s]*dinv[s]; agg = acc*dinv[n]
// out = x + relu(agg + b), all fused
__global__ void gather_agg(const int* __restrict__ off, const int* __restrict__ cnt,
                           const int* __restrict__ adj, const float* __restrict__ h,
                           const float* __restrict__ dinv, const float* __restrict__ x,
                           const float* __restrict__ b, float* __restrict__ out, int N) {
    int node = blockIdx.x * 4 + (threadIdx.x >> 6);
    int lane = threadIdx.x & 63;
    if (node >= N) return;
    int start = off[node];
    int m = cnt[node];
    float dn = dinv[node];
    float acc = h[node * DIM + lane] * dn;  // self loop (x dn at end -> dn^2)
    for (int c = 0; c < m; c += 64) {
        int rem = m - c;
        int take = rem < 64 ? rem : 64;
        int s = (lane < take) ? adj[start + c + lane] : 0;
        float w = (lane < take) ? dinv[s] : 0.f;
        for (int i = 0; i < take; ++i) {
            int si = __shfl(s, i);
            float wi = __shfl(w, i);
            acc += h[si * DIM + lane] * wi;
        }
    }
    float v = acc * dn + b[lane];
    out[node * DIM + lane] = x[node * DIM + lane] + fmaxf(v, 0.f);
}

extern "C" void kernel_launch(void* const* d_in, const int* in_sizes, int n_in,
                              void* d_out, int out_size, void* d_ws, size_t ws_size,
                              hipStream_t stream) {
    const float* x = (const float*)d_in[0];
    const int* ei  = (const int*)d_in[1];
    const float* W = (const float*)d_in[2];
    const float* b = (const float*)d_in[3];
    float* out = (float*)d_out;

    int N = in_sizes[0] / DIM;
    int E = in_sizes[1] / 2;

    char* ws = (char*)d_ws;
    size_t o = 0;
    float* h    = (float*)(ws + o); o += (size_t)N * DIM * sizeof(float);
    int* cnt    = (int*)(ws + o);   o += (size_t)N * sizeof(int);
    int* off    = (int*)(ws + o);   o += (size_t)N * sizeof(int);
    int* cursor = (int*)(ws + o);   o += (size_t)N * sizeof(int);
    float* dinv = (float*)(ws + o); o += (size_t)N * sizeof(float);
    int* bsum   = (int*)(ws + o);   o += 512 * sizeof(int);
    int* adj    = (int*)(ws + o);   o += (size_t)E * sizeof(int);

    int nb = (N + 255) / 256;  // scan blocks (391 <= 512)

    gcn_matmul<<<(N + 3) / 4, 256, 0, stream>>>(x, W, h, N);
    zero_i32<<<nb, 256, 0, stream>>>(cnt, N);
    count_dst<<<(E + 255) / 256, 256, 0, stream>>>(ei, cnt, E);
    calc_dinv<<<nb, 256, 0, stream>>>(cnt, dinv, N);
    scan_block<<<nb, 256, 0, stream>>>(cnt, off, bsum, N);
    scan_bsums<<<1, 512, 0, stream>>>(bsum, nb);
    scan_add<<<nb, 256, 0, stream>>>(off, cursor, bsum, N);
    fill_adj<<<(E + 255) / 256, 256, 0, stream>>>(ei, cursor, adj, E);
    gather_agg<<<(N + 3) / 4, 256, 0, stream>>>(off, cnt, adj, h, dinv, x, b, out, N);
}